// Round 20
// baseline (145.997 us; speedup 1.0000x reference)
//
#include <hip/hip_runtime.h>
#include <math.h>

#define D_IN  512
#define D_HID 64
#define D_OUT 40
#define CAP   64   // per-node edge capacity; deg ~ Poisson(16), max<<64

typedef __attribute__((ext_vector_type(8))) short bf16x8;
typedef __attribute__((ext_vector_type(4))) float f32x4;

static __device__ __forceinline__ unsigned short f2bf(float f) {
    unsigned u = __float_as_uint(f);
    return (unsigned short)((u + 0x7FFF + ((u >> 16) & 1)) >> 16);  // RNE
}
static __device__ __forceinline__ float bf2f(unsigned short h) {
    return __uint_as_float(((unsigned)h) << 16);
}

// ===========================================================================
// prep_all: zero cursor (N) | W1 -> w1T bf16 transposed | W2 -> w2T bf16
// ===========================================================================
__global__ __launch_bounds__(256)
void prep_all(int* __restrict__ cursor, const float* __restrict__ W1,
              unsigned short* __restrict__ w1T, const float* __restrict__ W2,
              unsigned short* __restrict__ w2T, int N) {
    const int i = blockIdx.x * blockDim.x + threadIdx.x;
    if (i < N) cursor[i] = 0;
    const int j = i - N;
    if (j >= 0 && j < D_IN * D_HID) {          // j = k*64 + col
        const int k = j >> 6, col = j & 63;
        w1T[col * D_IN + k] = f2bf(W1[j]);
    }
    const int l = j - D_IN * D_HID;
    if (l >= 0 && l < 48 * D_HID) {            // l = col*64 + k
        const int col = l >> 6, k = l & 63;
        w2T[l] = (col < D_OUT) ? f2bf(W2[k * D_OUT + col]) : 0;
    }
}

// ===========================================================================
// fat1: blocks [0, sBlocks) = capacity-CSR scatter (XCD-local, dispatched
// first); blocks [sBlocks, ...) = GEMM1 MFMA tiles.
//
// GEMM1 r19 scorecard: every per-chunk-barrier variant convoys (79-131 us).
// This round: W1 staged ONCE into 64 KB LDS (ONE barrier total), then a
// BARRIER-FREE K-loop — A-fragments direct from global (r11/r18 verified
// math) with compiler waitcnts only, B from LDS. #pragma unroll 2 keeps
// ~4 A-loads in flight/wave (r13's full-unroll VGPR blowup avoided);
// 8 waves/CU x 4 KB in flight >> 9 KB/CU BDP -> HBM-BW-bound, no convoy.
// ===========================================================================
__global__ __launch_bounds__(256)
void fat1(const float* __restrict__ x, const unsigned short* __restrict__ w1T,
          const float* __restrict__ b1, unsigned short* __restrict__ h1,
          const int* __restrict__ src, const int* __restrict__ dstA,
          const float* __restrict__ wm, int* __restrict__ cursor,
          unsigned* __restrict__ edges, int E, int N, int sBlocks) {
    __shared__ unsigned char lds[65536];  // gemm role: W1 64 cols x 512 k bf16, swizzled
    const int t = threadIdx.x;

    if ((int)blockIdx.x < sBlocks) {
        // ---------------- scatter: capacity-CSR, XCD-local ----------------
        const int slice = (N + 7) >> 3;
        const int lo = (blockIdx.x & 7) * slice;
        const int hi = min(N, lo + slice);
        const int nChunk = sBlocks >> 3;
        const int per = (E + nChunk - 1) / nChunk;
        const int beg = ((int)blockIdx.x >> 3) * per;
        const int end = min(E, beg + per);
        for (int e = beg + t; e < end; e += 256) {
            const int d = dstA[e];
            if (d >= lo && d < hi) {
                const int pos = atomicAdd(&cursor[d], 1);
                if (pos < CAP)
                    edges[(size_t)d * CAP + pos] =
                        ((unsigned)src[e] << 16) | (unsigned)f2bf(wm[e]);
            }
        }
        return;
    }

    // ---------------- GEMM1: h1[N,64] = x @ W1 + b1 ----------------
    const int lane = t & 63;
    const int wv = t >> 6;
    const int nodeBase = ((int)blockIdx.x - sBlocks) * 64;
    const int fr = lane & 15;
    const int fc = lane >> 4;

    // stage ALL of W1 once: 4096 16B-granules, 16/thread, coalesced
#pragma unroll
    for (int g = t; g < 4096; g += 256) {
        const int col = g >> 6, gs = g & 63;   // gs: k-granule (k = gs*8)
        const uint4 p = *reinterpret_cast<const uint4*>(w1T + (size_t)col * D_IN + gs * 8);
        *reinterpret_cast<uint4*>(lds + col * 1024 + ((gs * 16) ^ ((col & 7) << 4))) = p;
    }
    __syncthreads();  // the ONLY barrier

    int gn = nodeBase + wv * 16 + fr; if (gn >= N) gn = N - 1;
    const float* xrow = x + (size_t)gn * D_IN + fc * 8;

    f32x4 acc[4];
#pragma unroll
    for (int cg = 0; cg < 4; ++cg) acc[cg] = (f32x4){0.f, 0.f, 0.f, 0.f};

#pragma unroll 2
    for (int c = 0; c < 8; ++c) {
        const int kc = c * 64;
#pragma unroll
        for (int s = 0; s < 2; ++s) {
            const float4 a = *reinterpret_cast<const float4*>(xrow + kc + s * 32);
            const float4 b = *reinterpret_cast<const float4*>(xrow + kc + s * 32 + 4);
            uint4 pk;
            pk.x = (unsigned)f2bf(a.x) | ((unsigned)f2bf(a.y) << 16);
            pk.y = (unsigned)f2bf(a.z) | ((unsigned)f2bf(a.w) << 16);
            pk.z = (unsigned)f2bf(b.x) | ((unsigned)f2bf(b.y) << 16);
            pk.w = (unsigned)f2bf(b.z) | ((unsigned)f2bf(b.w) << 16);
            const bf16x8 afrag = *reinterpret_cast<const bf16x8*>(&pk);
            const int slot = s * 4 + fc;
#pragma unroll
            for (int cg = 0; cg < 4; ++cg) {
                const int brow = cg * 16 + fr;
                const bf16x8 bfrag = *reinterpret_cast<const bf16x8*>(
                    lds + brow * 1024 + kc * 2 + ((slot << 4) ^ ((brow & 7) << 4)));
                acc[cg] = __builtin_amdgcn_mfma_f32_16x16x32_bf16(afrag, bfrag, acc[cg], 0, 0, 0);
            }
        }
    }

    const int rq = lane >> 4;
#pragma unroll
    for (int cg = 0; cg < 4; ++cg) {
        const int col = cg * 16 + fr;
        const float bb = b1[col];
#pragma unroll
        for (int r = 0; r < 4; ++r) {
            const int node = nodeBase + wv * 16 + rq * 4 + r;
            if (node < N)
                h1[(size_t)node * D_HID + col] = f2bf(acc[cg][r] + bb);
        }
    }
}

// ===========================================================================
// Aggregation 1 (64 ch): wave/node, lane=channel. XCD-aligned node mapping
// (slice = bid%8 matches scatter's XCD-local writes). 8-deep gathers,
// fused relu + bf16 store.
// ===========================================================================
__global__ __launch_bounds__(256)
void agg_hid(const unsigned short* __restrict__ h, const unsigned* __restrict__ edges,
             const int* __restrict__ count, unsigned short* __restrict__ agg1, int N) {
    const int lane = threadIdx.x & 63;
    const int wv   = (threadIdx.x >> 6);
    const int slice = (N + 7) >> 3;                       // 6250
    const int local = ((int)blockIdx.x >> 3) * 4 + wv;    // node within slice
    if (local >= slice) return;
    const int n = ((int)blockIdx.x & 7) * slice + local;
    if (n >= N) return;
    const unsigned er = edges[(size_t)n * CAP + lane];
    const int cnt = min(count[n], CAP);
    float acc = 0.f;
    int j = 0;
    for (; j + 8 <= cnt; j += 8) {
        unsigned p[8];
#pragma unroll
        for (int u = 0; u < 8; ++u) p[u] = (unsigned)__shfl((int)er, j + u);
        float v[8];
#pragma unroll
        for (int u = 0; u < 8; ++u) v[u] = bf2f(h[(size_t)(p[u] >> 16) * D_HID + lane]);
#pragma unroll
        for (int u = 0; u < 8; ++u)
            acc += bf2f((unsigned short)(p[u] & 0xffff)) * v[u];
    }
    for (; j < cnt; ++j) {
        const unsigned p0 = (unsigned)__shfl((int)er, j);
        acc += bf2f((unsigned short)(p0 & 0xffff)) *
               bf2f(h[(size_t)(p0 >> 16) * D_HID + lane]);
    }
    agg1[(size_t)n * D_HID + lane] = f2bf(fmaxf(acc, 0.f));  // fused relu
}

// ===========================================================================
// GEMM2 (MFMA bf16): h2[N,40](bf16) = agg1relu[N,64] @ W2 + b2
// ===========================================================================
__global__ __launch_bounds__(256)
void gemm2_mfma(const unsigned short* __restrict__ agg1,
                const unsigned short* __restrict__ w2T,
                const float* __restrict__ b2, unsigned short* __restrict__ h2, int N) {
    __shared__ unsigned char lds[8192 + 6144];  // A @0 (64x128B), B @8192 (48x128B)
    const int t = threadIdx.x;
    const int lane = t & 63;
    const int wv = t >> 6;
    const int nodeBase = blockIdx.x * 64;

#pragma unroll
    for (int hh = 0; hh < 2; ++hh) {
        const int g = t + hh * 256;
        const int row = g >> 3, slot = g & 7;
        int gn = nodeBase + row; if (gn >= N) gn = N - 1;
        const uint4 p = *reinterpret_cast<const uint4*>(agg1 + (size_t)gn * D_HID + slot * 8);
        *reinterpret_cast<uint4*>(lds + row * 128 + ((slot << 4) ^ ((row & 7) << 4))) = p;
    }
    for (int g = t; g < 384; g += 256) {
        const int row = g >> 3, slot = g & 7;
        const uint4 p = *reinterpret_cast<const uint4*>(w2T + (size_t)row * D_HID + slot * 8);
        *reinterpret_cast<uint4*>(lds + 8192 + row * 128 + ((slot << 4) ^ ((row & 7) << 4))) = p;
    }
    __syncthreads();

    f32x4 acc[3];
#pragma unroll
    for (int cg = 0; cg < 3; ++cg) acc[cg] = (f32x4){0.f, 0.f, 0.f, 0.f};

    const int fr = lane & 15;
    const int fc = lane >> 4;
#pragma unroll
    for (int s = 0; s < 2; ++s) {
        const int slot = s * 4 + fc;
        const int arow = wv * 16 + fr;
        const bf16x8 afrag = *reinterpret_cast<const bf16x8*>(
            lds + arow * 128 + ((slot << 4) ^ ((arow & 7) << 4)));
#pragma unroll
        for (int cg = 0; cg < 3; ++cg) {
            const int brow = cg * 16 + fr;
            const bf16x8 bfrag = *reinterpret_cast<const bf16x8*>(
                lds + 8192 + brow * 128 + ((slot << 4) ^ ((brow & 7) << 4)));
            acc[cg] = __builtin_amdgcn_mfma_f32_16x16x32_bf16(afrag, bfrag, acc[cg], 0, 0, 0);
        }
    }

    const int rq = lane >> 4;
#pragma unroll
    for (int cg = 0; cg < 3; ++cg) {
        const int col = cg * 16 + fr;
        if (col < D_OUT) {
            const float bb = b2[col];
#pragma unroll
            for (int r = 0; r < 4; ++r) {
                const int node = nodeBase + wv * 16 + rq * 4 + r;
                if (node < N)
                    h2[(size_t)node * D_OUT + col] = f2bf(acc[cg][r] + bb);
            }
        }
    }
}

// ===========================================================================
// Aggregation 2 (40 ch) + log_softmax. XCD-aligned node mapping, 8-deep.
// ===========================================================================
__global__ __launch_bounds__(256)
void agg40_lsm(const unsigned short* __restrict__ h2, const unsigned* __restrict__ edges,
               const int* __restrict__ count, float* __restrict__ out, int N) {
    const int lane = threadIdx.x & 63;
    const int col  = (lane < D_OUT) ? lane : 0;  // clamped gather, no branch
    const int wv   = (threadIdx.x >> 6);
    const int slice = (N + 7) >> 3;
    const int local = ((int)blockIdx.x >> 3) * 4 + wv;
    if (local >= slice) return;
    const int n = ((int)blockIdx.x & 7) * slice + local;
    if (n >= N) return;
    const unsigned er = edges[(size_t)n * CAP + lane];
    const int cnt = min(count[n], CAP);
    float acc = 0.f;
    int j = 0;
    for (; j + 8 <= cnt; j += 8) {
        unsigned p[8];
#pragma unroll
        for (int u = 0; u < 8; ++u) p[u] = (unsigned)__shfl((int)er, j + u);
        float v[8];
#pragma unroll
        for (int u = 0; u < 8; ++u) v[u] = bf2f(h2[(size_t)(p[u] >> 16) * D_OUT + col]);
#pragma unroll
        for (int u = 0; u < 8; ++u)
            acc += bf2f((unsigned short)(p[u] & 0xffff)) * v[u];
    }
    for (; j < cnt; ++j) {
        const unsigned p0 = (unsigned)__shfl((int)er, j);
        acc += bf2f((unsigned short)(p0 & 0xffff)) *
               bf2f(h2[(size_t)(p0 >> 16) * D_OUT + col]);
    }
    const float v = (lane < D_OUT) ? acc : -INFINITY;
    float m = v;
#pragma unroll
    for (int o = 32; o > 0; o >>= 1) m = fmaxf(m, __shfl_xor(m, o, 64));
    float s = (lane < D_OUT) ? __expf(v - m) : 0.f;
#pragma unroll
    for (int o = 32; o > 0; o >>= 1) s += __shfl_xor(s, o, 64);
    if (lane < D_OUT) out[(size_t)n * D_OUT + lane] = v - m - __logf(s);
}

// ===========================================================================
extern "C" void kernel_launch(void* const* d_in, const int* in_sizes, int n_in,
                              void* d_out, int out_size, void* d_ws, size_t ws_size,
                              hipStream_t stream) {
    const float* x   = (const float*)d_in[0];
    const int*   ei  = (const int*)d_in[1];
    const float* wm  = (const float*)d_in[2];
    const float* W1  = (const float*)d_in[3];
    const float* b1  = (const float*)d_in[4];
    const float* W2  = (const float*)d_in[5];
    const float* b2  = (const float*)d_in[6];

    const int N = in_sizes[0] / D_IN;   // 50000
    const int E = in_sizes[2];          // 800000
    const int* srcIdx = ei;
    const int* dstIdx = ei + E;

    // workspace layout (16B-aligned blocks)
    unsigned short* w1T    = (unsigned short*)d_ws;                   // 64 KiB
    unsigned short* h1bf   = w1T + (size_t)D_HID * D_IN;              // N*64 bf16
    unsigned short* agg1bf = h1bf + (size_t)N * D_HID;                // N*64 bf16 (relu'd)
    unsigned* edges        = (unsigned*)(agg1bf + (size_t)N * D_HID); // N*CAP u32
    int*   cursor          = (int*)(edges + (size_t)N * CAP);         // N (= counts)
    unsigned short* w2T    = (unsigned short*)(cursor + N);           // 48*64 bf16
    unsigned short* h2bf   = h1bf;                                    // reuse (h1 dead after agg_hid)
    float* out             = (float*)d_out;

    const int g1Blocks = (N + 63) / 64;          // 782
    const int sBlocks  = 1024;                   // 128 chunks x 8 XCD slices
    const int prepWork = N + D_IN * D_HID + 48 * D_HID;
    const int slice = (N + 7) >> 3;              // 6250
    const int aggBlocks = ((slice + 3) / 4) * 8; // XCD-aligned agg grid

    prep_all<<<(prepWork + 255) / 256, 256, 0, stream>>>(cursor, W1, w1T, W2, w2T, N);
    fat1<<<sBlocks + g1Blocks, 256, 0, stream>>>(
        x, w1T, b1, h1bf, srcIdx, dstIdx, wm, cursor, edges, E, N, sBlocks);
    agg_hid<<<aggBlocks, 256, 0, stream>>>(h1bf, edges, cursor, agg1bf, N);
    gemm2_mfma<<<g1Blocks, 256, 0, stream>>>(agg1bf, w2T, b2, h2bf, N);
    agg40_lsm<<<aggBlocks, 256, 0, stream>>>(h2bf, edges, cursor, out, N);
}

// Round 21
// 118.587 us; speedup vs baseline: 1.2311x; 1.2311x over previous
//
#include <hip/hip_runtime.h>
#include <math.h>

#define D_IN  512
#define D_HID 64
#define D_OUT 40
#define CAP   64   // per-node edge capacity; deg ~ Poisson(16), max<<64

typedef __attribute__((ext_vector_type(8))) short bf16x8;
typedef __attribute__((ext_vector_type(4))) float f32x4;

static __device__ __forceinline__ unsigned short f2bf(float f) {
    unsigned u = __float_as_uint(f);
    return (unsigned short)((u + 0x7FFF + ((u >> 16) & 1)) >> 16);  // RNE
}
static __device__ __forceinline__ float bf2f(unsigned short h) {
    return __uint_as_float(((unsigned)h) << 16);
}

// ===========================================================================
// prep_all: zero cursor (N) | W1 -> w1T bf16 transposed | W2 -> w2T bf16
// ===========================================================================
__global__ __launch_bounds__(256)
void prep_all(int* __restrict__ cursor, const float* __restrict__ W1,
              unsigned short* __restrict__ w1T, const float* __restrict__ W2,
              unsigned short* __restrict__ w2T, int N) {
    const int i = blockIdx.x * blockDim.x + threadIdx.x;
    if (i < N) cursor[i] = 0;
    const int j = i - N;
    if (j >= 0 && j < D_IN * D_HID) {          // j = k*64 + col
        const int k = j >> 6, col = j & 63;
        w1T[col * D_IN + k] = f2bf(W1[j]);
    }
    const int l = j - D_IN * D_HID;
    if (l >= 0 && l < 48 * D_HID) {            // l = col*64 + k
        const int col = l >> 6, k = l & 63;
        w2T[l] = (col < D_OUT) ? f2bf(W2[k * D_OUT + col]) : 0;
    }
}

// ===========================================================================
// fat1: blocks [0, sBlocks) = capacity-CSR scatter (XCD-local, dispatched
// first so it overlaps); blocks [sBlocks, ...) = GEMM1 MFMA tiles.
// r15 structure EXACTLY (empirical optimum: 79.6 us vs 91-131 for all six
// redesigns r12/r16-r20). One local tweak: all 6 staging loads issued into
// named regs BEFORE pack/store (3x deeper MLP, same barriers, ~24 VGPR).
// ===========================================================================
__global__ __launch_bounds__(256)
void fat1(const float* __restrict__ x, const unsigned short* __restrict__ w1T,
          const float* __restrict__ b1, unsigned short* __restrict__ h1,
          const int* __restrict__ src, const int* __restrict__ dstA,
          const float* __restrict__ wm, int* __restrict__ cursor,
          unsigned* __restrict__ edges, int E, int N, int sBlocks) {
    __shared__ unsigned char lds[16384];  // gemm role: xs @0, ws @8192
    const int t = threadIdx.x;

    if ((int)blockIdx.x < sBlocks) {
        // ---------------- scatter: capacity-CSR, XCD-local ----------------
        const int slice = (N + 7) >> 3;
        const int lo = (blockIdx.x & 7) * slice;
        const int hi = min(N, lo + slice);
        const int nChunk = sBlocks >> 3;
        const int per = (E + nChunk - 1) / nChunk;
        const int beg = ((int)blockIdx.x >> 3) * per;
        const int end = min(E, beg + per);
        for (int e = beg + t; e < end; e += 256) {
            const int d = dstA[e];
            if (d >= lo && d < hi) {
                const int pos = atomicAdd(&cursor[d], 1);
                if (pos < CAP)
                    edges[(size_t)d * CAP + pos] =
                        ((unsigned)src[e] << 16) | (unsigned)f2bf(wm[e]);
            }
        }
        return;
    }

    // ---------------- GEMM1: h1[N,64] = x @ W1 + b1 (LDS-staged) ----------
    const int lane = t & 63;
    const int wv = t >> 6;
    const int nodeBase = ((int)blockIdx.x - sBlocks) * 64;

    // per-thread staging coords (constant across chunks)
    const int row0 = t >> 3, slot0 = t & 7;
    const int row1 = (t + 256) >> 3, slot1 = (t + 256) & 7;
    int gn0 = nodeBase + row0; if (gn0 >= N) gn0 = N - 1;
    int gn1 = nodeBase + row1; if (gn1 >= N) gn1 = N - 1;
    const float* xp0 = x + (size_t)gn0 * D_IN + slot0 * 8;
    const float* xp1 = x + (size_t)gn1 * D_IN + slot1 * 8;
    const unsigned short* wp0 = w1T + (size_t)row0 * D_IN + slot0 * 8;
    const unsigned short* wp1 = w1T + (size_t)row1 * D_IN + slot1 * 8;

    f32x4 acc[4];
#pragma unroll
    for (int cg = 0; cg < 4; ++cg) acc[cg] = (f32x4){0.f, 0.f, 0.f, 0.f};

    for (int k0 = 0; k0 < D_IN; k0 += 64) {
        // ---- issue ALL 6 independent loads before any pack/store
        const float4 xa0 = *reinterpret_cast<const float4*>(xp0 + k0);
        const float4 xb0 = *reinterpret_cast<const float4*>(xp0 + k0 + 4);
        const float4 xa1 = *reinterpret_cast<const float4*>(xp1 + k0);
        const float4 xb1 = *reinterpret_cast<const float4*>(xp1 + k0 + 4);
        const uint4  wr0 = *reinterpret_cast<const uint4*>(wp0 + k0);
        const uint4  wr1 = *reinterpret_cast<const uint4*>(wp1 + k0);

        uint4 p;
        p.x = (unsigned)f2bf(xa0.x) | ((unsigned)f2bf(xa0.y) << 16);
        p.y = (unsigned)f2bf(xa0.z) | ((unsigned)f2bf(xa0.w) << 16);
        p.z = (unsigned)f2bf(xb0.x) | ((unsigned)f2bf(xb0.y) << 16);
        p.w = (unsigned)f2bf(xb0.z) | ((unsigned)f2bf(xb0.w) << 16);
        *reinterpret_cast<uint4*>(lds + row0 * 128 + ((slot0 << 4) ^ ((row0 & 7) << 4))) = p;
        p.x = (unsigned)f2bf(xa1.x) | ((unsigned)f2bf(xa1.y) << 16);
        p.y = (unsigned)f2bf(xa1.z) | ((unsigned)f2bf(xa1.w) << 16);
        p.z = (unsigned)f2bf(xb1.x) | ((unsigned)f2bf(xb1.y) << 16);
        p.w = (unsigned)f2bf(xb1.z) | ((unsigned)f2bf(xb1.w) << 16);
        *reinterpret_cast<uint4*>(lds + row1 * 128 + ((slot1 << 4) ^ ((row1 & 7) << 4))) = p;
        *reinterpret_cast<uint4*>(lds + 8192 + row0 * 128 + ((slot0 << 4) ^ ((row0 & 7) << 4))) = wr0;
        *reinterpret_cast<uint4*>(lds + 8192 + row1 * 128 + ((slot1 << 4) ^ ((row1 & 7) << 4))) = wr1;
        __syncthreads();

        const int fr = lane & 15;
        const int fc = lane >> 4;
#pragma unroll
        for (int s = 0; s < 2; ++s) {
            const int slot = s * 4 + fc;
            const int arow = wv * 16 + fr;
            const bf16x8 afrag = *reinterpret_cast<const bf16x8*>(
                lds + arow * 128 + ((slot << 4) ^ ((arow & 7) << 4)));
#pragma unroll
            for (int cg = 0; cg < 4; ++cg) {
                const int brow = cg * 16 + fr;
                const bf16x8 bfrag = *reinterpret_cast<const bf16x8*>(
                    lds + 8192 + brow * 128 + ((slot << 4) ^ ((brow & 7) << 4)));
                acc[cg] = __builtin_amdgcn_mfma_f32_16x16x32_bf16(afrag, bfrag, acc[cg], 0, 0, 0);
            }
        }
        __syncthreads();
    }

    const int fr = lane & 15;
    const int rq = lane >> 4;
#pragma unroll
    for (int cg = 0; cg < 4; ++cg) {
        const int col = cg * 16 + fr;
        const float bb = b1[col];
#pragma unroll
        for (int r = 0; r < 4; ++r) {
            const int node = nodeBase + wv * 16 + rq * 4 + r;
            if (node < N)
                h1[(size_t)node * D_HID + col] = f2bf(acc[cg][r] + bb);
        }
    }
}

// ===========================================================================
// Aggregation 1 (64 ch): wave/node, lane=channel. XCD-aligned node mapping
// (slice = bid%8 matches scatter's XCD-local writes). 8-deep gathers,
// fused relu + bf16 store.
// ===========================================================================
__global__ __launch_bounds__(256)
void agg_hid(const unsigned short* __restrict__ h, const unsigned* __restrict__ edges,
             const int* __restrict__ count, unsigned short* __restrict__ agg1, int N) {
    const int lane = threadIdx.x & 63;
    const int wv   = (threadIdx.x >> 6);
    const int slice = (N + 7) >> 3;                       // 6250
    const int local = ((int)blockIdx.x >> 3) * 4 + wv;    // node within slice
    if (local >= slice) return;
    const int n = ((int)blockIdx.x & 7) * slice + local;
    if (n >= N) return;
    const unsigned er = edges[(size_t)n * CAP + lane];
    const int cnt = min(count[n], CAP);
    float acc = 0.f;
    int j = 0;
    for (; j + 8 <= cnt; j += 8) {
        unsigned p[8];
#pragma unroll
        for (int u = 0; u < 8; ++u) p[u] = (unsigned)__shfl((int)er, j + u);
        float v[8];
#pragma unroll
        for (int u = 0; u < 8; ++u) v[u] = bf2f(h[(size_t)(p[u] >> 16) * D_HID + lane]);
#pragma unroll
        for (int u = 0; u < 8; ++u)
            acc += bf2f((unsigned short)(p[u] & 0xffff)) * v[u];
    }
    for (; j < cnt; ++j) {
        const unsigned p0 = (unsigned)__shfl((int)er, j);
        acc += bf2f((unsigned short)(p0 & 0xffff)) *
               bf2f(h[(size_t)(p0 >> 16) * D_HID + lane]);
    }
    agg1[(size_t)n * D_HID + lane] = f2bf(fmaxf(acc, 0.f));  // fused relu
}

// ===========================================================================
// GEMM2 (MFMA bf16): h2[N,40](bf16) = agg1relu[N,64] @ W2 + b2
// ===========================================================================
__global__ __launch_bounds__(256)
void gemm2_mfma(const unsigned short* __restrict__ agg1,
                const unsigned short* __restrict__ w2T,
                const float* __restrict__ b2, unsigned short* __restrict__ h2, int N) {
    __shared__ unsigned char lds[8192 + 6144];  // A @0 (64x128B), B @8192 (48x128B)
    const int t = threadIdx.x;
    const int lane = t & 63;
    const int wv = t >> 6;
    const int nodeBase = blockIdx.x * 64;

#pragma unroll
    for (int hh = 0; hh < 2; ++hh) {
        const int g = t + hh * 256;
        const int row = g >> 3, slot = g & 7;
        int gn = nodeBase + row; if (gn >= N) gn = N - 1;
        const uint4 p = *reinterpret_cast<const uint4*>(agg1 + (size_t)gn * D_HID + slot * 8);
        *reinterpret_cast<uint4*>(lds + row * 128 + ((slot << 4) ^ ((row & 7) << 4))) = p;
    }
    for (int g = t; g < 384; g += 256) {
        const int row = g >> 3, slot = g & 7;
        const uint4 p = *reinterpret_cast<const uint4*>(w2T + (size_t)row * D_HID + slot * 8);
        *reinterpret_cast<uint4*>(lds + 8192 + row * 128 + ((slot << 4) ^ ((row & 7) << 4))) = p;
    }
    __syncthreads();

    f32x4 acc[3];
#pragma unroll
    for (int cg = 0; cg < 3; ++cg) acc[cg] = (f32x4){0.f, 0.f, 0.f, 0.f};

    const int fr = lane & 15;
    const int fc = lane >> 4;
#pragma unroll
    for (int s = 0; s < 2; ++s) {
        const int slot = s * 4 + fc;
        const int arow = wv * 16 + fr;
        const bf16x8 afrag = *reinterpret_cast<const bf16x8*>(
            lds + arow * 128 + ((slot << 4) ^ ((arow & 7) << 4)));
#pragma unroll
        for (int cg = 0; cg < 3; ++cg) {
            const int brow = cg * 16 + fr;
            const bf16x8 bfrag = *reinterpret_cast<const bf16x8*>(
                lds + 8192 + brow * 128 + ((slot << 4) ^ ((brow & 7) << 4)));
            acc[cg] = __builtin_amdgcn_mfma_f32_16x16x32_bf16(afrag, bfrag, acc[cg], 0, 0, 0);
        }
    }

    const int rq = lane >> 4;
#pragma unroll
    for (int cg = 0; cg < 3; ++cg) {
        const int col = cg * 16 + fr;
        if (col < D_OUT) {
            const float bb = b2[col];
#pragma unroll
            for (int r = 0; r < 4; ++r) {
                const int node = nodeBase + wv * 16 + rq * 4 + r;
                if (node < N)
                    h2[(size_t)node * D_OUT + col] = f2bf(acc[cg][r] + bb);
            }
        }
    }
}

// ===========================================================================
// Aggregation 2 (40 ch) + log_softmax. XCD-aligned node mapping, 8-deep.
// ===========================================================================
__global__ __launch_bounds__(256)
void agg40_lsm(const unsigned short* __restrict__ h2, const unsigned* __restrict__ edges,
               const int* __restrict__ count, float* __restrict__ out, int N) {
    const int lane = threadIdx.x & 63;
    const int col  = (lane < D_OUT) ? lane : 0;  // clamped gather, no branch
    const int wv   = (threadIdx.x >> 6);
    const int slice = (N + 7) >> 3;
    const int local = ((int)blockIdx.x >> 3) * 4 + wv;
    if (local >= slice) return;
    const int n = ((int)blockIdx.x & 7) * slice + local;
    if (n >= N) return;
    const unsigned er = edges[(size_t)n * CAP + lane];
    const int cnt = min(count[n], CAP);
    float acc = 0.f;
    int j = 0;
    for (; j + 8 <= cnt; j += 8) {
        unsigned p[8];
#pragma unroll
        for (int u = 0; u < 8; ++u) p[u] = (unsigned)__shfl((int)er, j + u);
        float v[8];
#pragma unroll
        for (int u = 0; u < 8; ++u) v[u] = bf2f(h2[(size_t)(p[u] >> 16) * D_OUT + col]);
#pragma unroll
        for (int u = 0; u < 8; ++u)
            acc += bf2f((unsigned short)(p[u] & 0xffff)) * v[u];
    }
    for (; j < cnt; ++j) {
        const unsigned p0 = (unsigned)__shfl((int)er, j);
        acc += bf2f((unsigned short)(p0 & 0xffff)) *
               bf2f(h2[(size_t)(p0 >> 16) * D_OUT + col]);
    }
    const float v = (lane < D_OUT) ? acc : -INFINITY;
    float m = v;
#pragma unroll
    for (int o = 32; o > 0; o >>= 1) m = fmaxf(m, __shfl_xor(m, o, 64));
    float s = (lane < D_OUT) ? __expf(v - m) : 0.f;
#pragma unroll
    for (int o = 32; o > 0; o >>= 1) s += __shfl_xor(s, o, 64);
    if (lane < D_OUT) out[(size_t)n * D_OUT + lane] = v - m - __logf(s);
}

// ===========================================================================
extern "C" void kernel_launch(void* const* d_in, const int* in_sizes, int n_in,
                              void* d_out, int out_size, void* d_ws, size_t ws_size,
                              hipStream_t stream) {
    const float* x   = (const float*)d_in[0];
    const int*   ei  = (const int*)d_in[1];
    const float* wm  = (const float*)d_in[2];
    const float* W1  = (const float*)d_in[3];
    const float* b1  = (const float*)d_in[4];
    const float* W2  = (const float*)d_in[5];
    const float* b2  = (const float*)d_in[6];

    const int N = in_sizes[0] / D_IN;   // 50000
    const int E = in_sizes[2];          // 800000
    const int* srcIdx = ei;
    const int* dstIdx = ei + E;

    // workspace layout (16B-aligned blocks)
    unsigned short* w1T    = (unsigned short*)d_ws;                   // 64 KiB
    unsigned short* h1bf   = w1T + (size_t)D_HID * D_IN;              // N*64 bf16
    unsigned short* agg1bf = h1bf + (size_t)N * D_HID;                // N*64 bf16 (relu'd)
    unsigned* edges        = (unsigned*)(agg1bf + (size_t)N * D_HID); // N*CAP u32
    int*   cursor          = (int*)(edges + (size_t)N * CAP);         // N (= counts)
    unsigned short* w2T    = (unsigned short*)(cursor + N);           // 48*64 bf16
    unsigned short* h2bf   = h1bf;                                    // reuse (h1 dead after agg_hid)
    float* out             = (float*)d_out;

    const int g1Blocks = (N + 63) / 64;          // 782
    const int sBlocks  = 1024;                   // 128 chunks x 8 XCD slices
    const int prepWork = N + D_IN * D_HID + 48 * D_HID;
    const int slice = (N + 7) >> 3;              // 6250
    const int aggBlocks = ((slice + 3) / 4) * 8; // XCD-aligned agg grid

    prep_all<<<(prepWork + 255) / 256, 256, 0, stream>>>(cursor, W1, w1T, W2, w2T, N);
    fat1<<<sBlocks + g1Blocks, 256, 0, stream>>>(
        x, w1T, b1, h1bf, srcIdx, dstIdx, wm, cursor, edges, E, N, sBlocks);
    agg_hid<<<aggBlocks, 256, 0, stream>>>(h1bf, edges, cursor, agg1bf, N);
    gemm2_mfma<<<g1Blocks, 256, 0, stream>>>(agg1bf, w2T, b2, h2bf, N);
    agg40_lsm<<<aggBlocks, 256, 0, stream>>>(h2bf, edges, cursor, out, N);
}